// Round 10
// baseline (647.358 us; speedup 1.0000x reference)
//
#include <hip/hip_runtime.h>
#include <hip/hip_fp16.h>

#define N_NODES 100000
#define N_EDGES 3200000
#define BGR 64
#define DIM 16
#define NFP 33
#define ROW1 32
#define H1STR 36
#define EMB 128
#define MAXLEN 3000
#define LOCLEN 2998
#define NF 32
#define KS 8
#define OUTT 121
#define FC_IN 3872
#define BN_EPSV 1e-5f
#define POOL_CHUNK 256
#define POOL_BLKS 391
#define MLPB 391
#define AGGB1 6250
#define AGGB16 3125
// binned CSR build
#define NBIN 391
#define BCNT_BLK 512
#define P1_CHUNK 4096
#define P1_BLOCKS 782
#define MAXBIN 9088
// fc K-split
#define NKC 32
#define KCH 121
#define WDEC (1.f / 32767.f)
#define SEG_G 8

// ---------------- merged bincnt + bucket (independent preprocessing) ----------------
__global__ void __launch_bounds__(256) k_pre1(const int* __restrict__ dst,
                                              int* __restrict__ bh,
                                              const int* __restrict__ rg,
                                              const int* __restrict__ rl,
                                              int* __restrict__ blg, int* __restrict__ bpg,
                                              int* __restrict__ bll, int* __restrict__ bpl) {
    __shared__ int sh[NBIN];
    int t = threadIdx.x, bid = blockIdx.x;
    if (bid < BCNT_BLK) {
        for (int b = t; b < NBIN; b += 256) sh[b] = 0;
        __syncthreads();
        int e0 = bid * (N_EDGES / BCNT_BLK);
        int e1 = e0 + (N_EDGES / BCNT_BLK);
        for (int e = e0 + t; e < e1; e += 256) atomicAdd(&sh[dst[e] >> 8], 1);
        __syncthreads();
        for (int b = t; b < NBIN; b += 256) bh[b * BCNT_BLK + bid] = sh[b];
    } else {
        int idx = bid - BCNT_BLK;
        int which = idx >> 6, b = idx & 63;
        const int* tok = which ? rl : rg;
        int L = which ? LOCLEN : MAXLEN;
        int V = which ? 65 : 5;
        int* blist = which ? bll : blg;
        int* bptr = which ? bpl : bpg;
        int* hist = sh;
        int* cursor = sh + 70;
        if (t < V) hist[t] = 0;
        __syncthreads();
        for (int l = t; l < L; l += 256) atomicAdd(&hist[tok[b * L + l]], 1);
        __syncthreads();
        if (t == 0) {
            int run = 0;
            for (int v = 0; v < V; v++) {
                cursor[v] = run;
                bptr[b * (V + 1) + v] = run;
                run += hist[v];
            }
            bptr[b * (V + 1) + V] = run;
        }
        __syncthreads();
        for (int l = t; l < L; l += 256) {
            int v = tok[b * L + l];
            int p = atomicAdd(&cursor[v], 1);
            blist[b * L + p] = l;
        }
    }
}

__global__ void __launch_bounds__(512) k_binscan(const int* __restrict__ bh,
                                                 int* __restrict__ binoff,
                                                 int* __restrict__ bincur) {
    __shared__ int sc[512];
    int t = threadIdx.x;
    int s = 0;
    if (t < NBIN) {
        const int4* row = (const int4*)(bh + t * BCNT_BLK);
        #pragma unroll 4
        for (int k = 0; k < BCNT_BLK / 4; k++) {
            int4 v = row[k];
            s += v.x + v.y + v.z + v.w;
        }
    }
    sc[t] = s;
    __syncthreads();
    for (int off = 1; off < 512; off <<= 1) {
        int v = (t >= off) ? sc[t - off] : 0;
        __syncthreads();
        sc[t] += v;
        __syncthreads();
    }
    int excl = sc[t] - s;
    if (t <= NBIN) binoff[t] = excl;
    if (t < NBIN) bincur[t] = excl;
}

// pass 1: single coalesced read -> LDS-staged records -> LDS rank -> coalesced write.
__global__ void __launch_bounds__(256) k_part1(const int* __restrict__ src,
                                               const int* __restrict__ dst,
                                               const float* __restrict__ w,
                                               int* __restrict__ bincur,
                                               int2* __restrict__ tmp_sw) {
    __shared__ int2 srec[P1_CHUNK];
    __shared__ unsigned short sbin[P1_CHUNK];
    __shared__ unsigned short sperm[P1_CHUNK];
    __shared__ int hist[NBIN];
    __shared__ int off[NBIN];
    __shared__ int cur[NBIN];
    __shared__ int base[NBIN];
    __shared__ int sc[512];
    int t = threadIdx.x;
    int g0 = blockIdx.x * P1_CHUNK;
    int cn = N_EDGES - g0; if (cn > P1_CHUNK) cn = P1_CHUNK;
    for (int b = t; b < NBIN; b += 256) hist[b] = 0;
    __syncthreads();
    for (int j = t; j < cn; j += 256) {
        int d = dst[g0 + j];
        int b = d >> 8;
        sbin[j] = (unsigned short)b;
        srec[j] = make_int2(src[g0 + j] | ((d & 255) << 20), __float_as_int(w[g0 + j]));
        atomicAdd(&hist[b], 1);
    }
    __syncthreads();
    sc[t] = (t < NBIN) ? hist[t] : 0;
    sc[256 + t] = (256 + t < NBIN) ? hist[256 + t] : 0;
    __syncthreads();
    for (int o = 1; o <= 256; o <<= 1) {
        int v0 = (t >= o) ? sc[t - o] : 0;
        int v1 = sc[256 + t - o];
        __syncthreads();
        sc[t] += v0;
        sc[256 + t] += v1;
        __syncthreads();
    }
    for (int b = t; b < NBIN; b += 256) {
        int e = sc[b] - hist[b];
        off[b] = e;
        cur[b] = e;
        int c = hist[b];
        base[b] = c ? atomicAdd(&bincur[b], c) : 0;
    }
    __syncthreads();
    for (int j = t; j < cn; j += 256) {
        int p = atomicAdd(&cur[sbin[j]], 1);
        sperm[p] = (unsigned short)j;
    }
    __syncthreads();
    for (int p = t; p < cn; p += 256) {
        int j = sperm[p];
        int b = sbin[j];
        tmp_sw[base[b] + (p - off[b])] = srec[j];
    }
}

// pass 2: per-bin fine sort + ptr; emit compact 4B edge records src(17) | wq(15)
__global__ void __launch_bounds__(256) k_part2(const int2* __restrict__ tmp_sw,
                                               const int* __restrict__ binoff,
                                               unsigned* __restrict__ er,
                                               int* __restrict__ ptr) {
    __shared__ unsigned char sdl[MAXBIN];
    __shared__ unsigned short perm[MAXBIN];
    __shared__ int hist[256];
    __shared__ int cur[256];
    __shared__ int sc[256];
    int t = threadIdx.x, b = blockIdx.x;
    int nlo = b << 8;
    int e0 = binoff[b], e1 = binoff[b + 1];
    int cnt = e1 - e0;
    int stage = cnt < MAXBIN ? cnt : MAXBIN;
    hist[t] = 0;
    __syncthreads();
    for (int j = t; j < stage; j += 256) {
        unsigned char dl = (unsigned char)((tmp_sw[e0 + j].x >> 20) & 255);
        sdl[j] = dl;
        atomicAdd(&hist[dl], 1);
    }
    for (int j = stage + t; j < cnt; j += 256)
        atomicAdd(&hist[(tmp_sw[e0 + j].x >> 20) & 255], 1);
    __syncthreads();
    int v = hist[t];
    sc[t] = v;
    __syncthreads();
    for (int off = 1; off < 256; off <<= 1) {
        int u = (t >= off) ? sc[t - off] : 0;
        __syncthreads();
        sc[t] += u;
        __syncthreads();
    }
    int excl = sc[t] - v;
    cur[t] = excl;
    if (nlo + t < N_NODES) ptr[nlo + t] = e0 + excl;
    if (b == NBIN - 1 && t == 0) ptr[N_NODES] = N_EDGES;
    __syncthreads();
    for (int j = t; j < stage; j += 256) {
        int p = atomicAdd(&cur[sdl[j]], 1);
        perm[p] = (unsigned short)j;
    }
    __syncthreads();
    for (int j = stage + t; j < cnt; j += 256) {
        int2 sw = tmp_sw[e0 + j];
        int p = atomicAdd(&cur[(sw.x >> 20) & 255], 1);
        unsigned wq = (unsigned)(__int_as_float(sw.y) * 32767.f + 0.5f);
        er[e0 + p] = ((unsigned)sw.x & 0x1FFFFu) | (wq << 17);
    }
    for (int p = t; p < stage; p += 256) {
        int2 sw = tmp_sw[e0 + perm[p]];
        unsigned wq = (unsigned)(__int_as_float(sw.y) * 32767.f + 0.5f);
        er[e0 + p] = ((unsigned)sw.x & 0x1FFFFu) | (wq << 17);
    }
}

// ---------------- merged conv-weight transpose + pro_x fp16 conversion ----------------
__global__ void __launch_bounds__(256) k_pre2(const float* __restrict__ cw1,
                                              const float* __restrict__ cw2,
                                              float* __restrict__ cwTg,
                                              float* __restrict__ cwTl,
                                              const float* __restrict__ x,
                                              __half* __restrict__ xh,
                                              __half* __restrict__ xh32) {
    int bid = blockIdx.x, t = threadIdx.x;
    if (bid < MAXLEN) {
        cwTg[bid * 256 + t] = cw1[(t >> 3) * (MAXLEN * KS) + bid * KS + (t & 7)];
    } else if (bid < MAXLEN + LOCLEN) {
        int ll = bid - MAXLEN;
        cwTl[ll * 256 + t] = cw2[(t >> 3) * (LOCLEN * KS) + ll * KS + (t & 7)];
    } else {
        int i = (bid - (MAXLEN + LOCLEN)) * 256 + t;
        if (i < N_NODES * NFP) {
            int n = i / NFP, f = i - n * NFP;
            __half v = __float2half(x[i]);
            if (f < 32) xh[n * ROW1 + f] = v;
            else xh32[n] = v;
        }
    }
}

// 8-feature accumulate helpers
__device__ __forceinline__ void acc8p(float a[8], uint4 r, float wv,
                                      const float* __restrict__ ewf,
                                      const float* __restrict__ ebf) {
    float2 f01 = __half22float2(*(__half2*)&r.x);
    float2 f23 = __half22float2(*(__half2*)&r.y);
    float2 f45 = __half22float2(*(__half2*)&r.z);
    float2 f67 = __half22float2(*(__half2*)&r.w);
    float x[8] = {f01.x, f01.y, f23.x, f23.y, f45.x, f45.y, f67.x, f67.y};
    #pragma unroll
    for (int j = 0; j < 8; j++)
        a[j] += fmaxf(x[j] + fmaf(wv, ewf[j], ebf[j]), 0.f);
}

__device__ __forceinline__ void acc8s(float a[8], uint4 r, float wv,
                                      const float* __restrict__ scf,
                                      const float* __restrict__ cbf,
                                      const float* __restrict__ ewf) {
    float2 f01 = __half22float2(*(__half2*)&r.x);
    float2 f23 = __half22float2(*(__half2*)&r.y);
    float2 f45 = __half22float2(*(__half2*)&r.z);
    float2 f67 = __half22float2(*(__half2*)&r.w);
    float x[8] = {f01.x, f01.y, f23.x, f23.y, f45.x, f45.y, f67.x, f67.y};
    #pragma unroll
    for (int j = 0; j < 8; j++)
        a[j] += fmaxf(fmaf(x[j], scf[j], fmaf(wv, ewf[j], cbf[j])), 0.f);
}

// ---------------- layer-1 aggregate (33 feats) [round-8 proven, unchanged] ----------------
__global__ void __launch_bounds__(256) k_agg1(
    const __half* __restrict__ xh, const __half* __restrict__ xh32,
    const int* __restrict__ ptr, const unsigned* __restrict__ er,
    const float* __restrict__ ew, const float* __restrict__ ebv,
    const float* __restrict__ epsp, float* __restrict__ h) {
    int t = threadIdx.x;
    int wave = t >> 6, lane = t & 63;
    int nl = lane >> 4;
    int slot = (lane >> 2) & 3;
    int q = lane & 3;
    float ewf[8], ebf[8];
    #pragma unroll
    for (int j = 0; j < 8; j++) { ewf[j] = ew[q * 8 + j]; ebf[j] = ebv[q * 8 + j]; }
    float ew32 = ew[32], eb32 = ebv[32];
    float ep = 1.f + epsp[0];
    int node = blockIdx.x * 16 + wave * 4 + nl;
    int e0 = ptr[node], e1 = ptr[node + 1];
    float a[8] = {0, 0, 0, 0, 0, 0, 0, 0};
    float a32 = 0.f;
    int i = e0 + slot;
    while (i + 4 < e1) {
        unsigned ev0 = er[i];
        unsigned ev1 = er[i + 4];
        int s0 = ev0 & 0x1FFFF, s1 = ev1 & 0x1FFFF;
        float wv0 = (float)(ev0 >> 17) * WDEC;
        float wv1 = (float)(ev1 >> 17) * WDEC;
        uint4 r0 = *(const uint4*)(xh + s0 * ROW1 + q * 8);
        uint4 r1 = *(const uint4*)(xh + s1 * ROW1 + q * 8);
        acc8p(a, r0, wv0, ewf, ebf);
        acc8p(a, r1, wv1, ewf, ebf);
        if (q == 0) {
            a32 += fmaxf(__half2float(xh32[s0]) + fmaf(wv0, ew32, eb32), 0.f);
            a32 += fmaxf(__half2float(xh32[s1]) + fmaf(wv1, ew32, eb32), 0.f);
        }
        i += 8;
    }
    if (i < e1) {
        unsigned ev = er[i];
        int s = ev & 0x1FFFF;
        float wv = (float)(ev >> 17) * WDEC;
        uint4 r = *(const uint4*)(xh + s * ROW1 + q * 8);
        acc8p(a, r, wv, ewf, ebf);
        if (q == 0)
            a32 += fmaxf(__half2float(xh32[s]) + fmaf(wv, ew32, eb32), 0.f);
    }
    #pragma unroll
    for (int j = 0; j < 8; j++) {
        a[j] += __shfl_xor(a[j], 4);
        a[j] += __shfl_xor(a[j], 8);
    }
    a32 += __shfl_xor(a32, 4);
    a32 += __shfl_xor(a32, 8);
    if (slot == 0) {
        uint4 sraw = *(const uint4*)(xh + node * ROW1 + q * 8);
        float2 s01 = __half22float2(*(__half2*)&sraw.x);
        float2 s23 = __half22float2(*(__half2*)&sraw.y);
        float2 s45 = __half22float2(*(__half2*)&sraw.z);
        float2 s67 = __half22float2(*(__half2*)&sraw.w);
        float* hp = h + node * H1STR + q * 8;
        *(float4*)hp = make_float4(ep * s01.x + a[0], ep * s01.y + a[1],
                                   ep * s23.x + a[2], ep * s23.y + a[3]);
        *(float4*)(hp + 4) = make_float4(ep * s45.x + a[4], ep * s45.y + a[5],
                                         ep * s67.x + a[6], ep * s67.y + a[7]);
        if (q == 0)
            h[node * H1STR + 32] = ep * __half2float(xh32[node]) + a32;
    }
}

// ---------------- fused layer 2-5: aggregate + BN-folded + 16x16 MLP in-register ----------------
__global__ void __launch_bounds__(256) k_f16(
    const __half* __restrict__ zin, const int* __restrict__ ptr,
    const unsigned* __restrict__ er,
    const float* __restrict__ ew, const float* __restrict__ ebv,
    const float* __restrict__ epsp,
    const float* __restrict__ bnstat, const float* __restrict__ gamma,
    const float* __restrict__ beta,
    const float* __restrict__ W1, const float* __restrict__ b1,
    const float* __restrict__ W2, const float* __restrict__ b2,
    __half* __restrict__ zout, float* __restrict__ bnout) {
    __shared__ float W1s[256], W2s[256], b1s[16], b2s[16];
    __shared__ float red[4][32];
    int t = threadIdx.x;
    W1s[t] = W1[t];
    W2s[t] = W2[t];
    if (t < 16) { b1s[t] = b1[t]; b2s[t] = b2[t]; }
    __syncthreads();
    int wave = t >> 6, lane = t & 63;
    int nl = lane >> 3;
    int slot = (lane >> 1) & 3;
    int hh = lane & 1;
    float ep = 1.f + epsp[0];
    const float invn = 1.f / (float)N_NODES;
    float scf[8], shf[8], cbf[8], ewf[8];
    #pragma unroll
    for (int j = 0; j < 8; j++) {
        int f = hh * 8 + j;
        float mu = bnstat[f] * invn;
        float var = bnstat[DIM + f] * invn - mu * mu;
        float sc = gamma[f] * rsqrtf(var + BN_EPSV);
        scf[j] = sc;
        shf[j] = beta[f] - mu * sc;
        cbf[j] = shf[j] + ebv[f];
        ewf[j] = ew[f];
    }
    int node = blockIdx.x * 32 + wave * 8 + nl;
    int e0 = ptr[node], e1 = ptr[node + 1];
    float a[8] = {0, 0, 0, 0, 0, 0, 0, 0};
    int i = e0 + slot;
    while (i + 4 < e1) {
        unsigned ev0 = er[i];
        unsigned ev1 = er[i + 4];
        float wv0 = (float)(ev0 >> 17) * WDEC;
        float wv1 = (float)(ev1 >> 17) * WDEC;
        uint4 r0 = *(const uint4*)(zin + (ev0 & 0x1FFFFu) * DIM + hh * 8);
        uint4 r1 = *(const uint4*)(zin + (ev1 & 0x1FFFFu) * DIM + hh * 8);
        acc8s(a, r0, wv0, scf, cbf, ewf);
        acc8s(a, r1, wv1, scf, cbf, ewf);
        i += 8;
    }
    if (i < e1) {
        unsigned ev = er[i];
        float wv = (float)(ev >> 17) * WDEC;
        uint4 r = *(const uint4*)(zin + (ev & 0x1FFFFu) * DIM + hh * 8);
        acc8s(a, r, wv, scf, cbf, ewf);
    }
    #pragma unroll
    for (int j = 0; j < 8; j++) a[j] += __shfl_xor(a[j], 2);
    #pragma unroll
    for (int j = 0; j < 8; j++) a[j] += __shfl_xor(a[j], 4);
    // epilogue + MLP: ALL lanes execute (slot!=0 lanes carry garbage, excluded at store/BN)
    uint4 sraw = *(const uint4*)(zin + node * DIM + hh * 8);
    float2 s01 = __half22float2(*(__half2*)&sraw.x);
    float2 s23 = __half22float2(*(__half2*)&sraw.y);
    float2 s45 = __half22float2(*(__half2*)&sraw.z);
    float2 s67 = __half22float2(*(__half2*)&sraw.w);
    float xs[8] = {s01.x, s01.y, s23.x, s23.y, s45.x, s45.y, s67.x, s67.y};
    float o8[8];
    #pragma unroll
    for (int j = 0; j < 8; j++)
        o8[j] = ep * fmaf(xs[j], scf[j], shf[j]) + a[j];
    float oth[8];
    #pragma unroll
    for (int j = 0; j < 8; j++) oth[j] = __shfl_xor(o8[j], 1);
    float hv[16];
    if (hh == 0) {
        #pragma unroll
        for (int j = 0; j < 8; j++) { hv[j] = o8[j]; hv[8 + j] = oth[j]; }
    } else {
        #pragma unroll
        for (int j = 0; j < 8; j++) { hv[j] = oth[j]; hv[8 + j] = o8[j]; }
    }
    int ob = hh * 8;
    float tv[8];
    #pragma unroll
    for (int j = 0; j < 8; j++) {
        float s = b1s[ob + j];
        #pragma unroll
        for (int f = 0; f < 16; f++) s += hv[f] * W1s[f * 16 + ob + j];
        tv[j] = fmaxf(s, 0.f);
    }
    float tvo[8];
    #pragma unroll
    for (int j = 0; j < 8; j++) tvo[j] = __shfl_xor(tv[j], 1);
    float tf[16];
    if (hh == 0) {
        #pragma unroll
        for (int j = 0; j < 8; j++) { tf[j] = tv[j]; tf[8 + j] = tvo[j]; }
    } else {
        #pragma unroll
        for (int j = 0; j < 8; j++) { tf[j] = tvo[j]; tf[8 + j] = tv[j]; }
    }
    float zv[8];
    #pragma unroll
    for (int j = 0; j < 8; j++) {
        float s = b2s[ob + j];
        #pragma unroll
        for (int f = 0; f < 16; f++) s += tf[f] * W2s[f * 16 + ob + j];
        zv[j] = fmaxf(s, 0.f);
    }
    if (slot == 0) {
        __half2 p[4];
        #pragma unroll
        for (int j = 0; j < 4; j++) p[j] = __floats2half2_rn(zv[2 * j], zv[2 * j + 1]);
        *(uint4*)(zout + node * DIM + hh * 8) = *(uint4*)&p[0];
    }
    float zs[8], zq[8];
    bool act = (slot == 0);
    #pragma unroll
    for (int j = 0; j < 8; j++) {
        zs[j] = act ? zv[j] : 0.f;
        zq[j] = act ? zv[j] * zv[j] : 0.f;
    }
    #pragma unroll
    for (int m = 8; m <= 32; m <<= 1) {
        #pragma unroll
        for (int j = 0; j < 8; j++) {
            zs[j] += __shfl_xor(zs[j], m);
            zq[j] += __shfl_xor(zq[j], m);
        }
    }
    if (lane < 2) {
        #pragma unroll
        for (int j = 0; j < 8; j++) {
            red[wave][lane * 8 + j] = zs[j];
            red[wave][16 + lane * 8 + j] = zq[j];
        }
    }
    __syncthreads();
    if (t < 32)
        atomicAdd(&bnout[t], red[0][t] + red[1][t] + red[2][t] + red[3][t]);
}

// ---------------- mlp1 (layer-1 MLP, unchanged) ----------------
__device__ __forceinline__ void mlp_bn_tail(float zv[16], bool active, int t,
                                            float* __restrict__ bnstat) {
    __shared__ float red[4][32];
    float zs[16], zq[16];
    #pragma unroll
    for (int o = 0; o < 16; o++) {
        zs[o] = active ? zv[o] : 0.f;
        zq[o] = active ? zv[o] * zv[o] : 0.f;
    }
    #pragma unroll
    for (int m = 1; m <= 32; m <<= 1) {
        #pragma unroll
        for (int o = 0; o < 16; o++) {
            zs[o] += __shfl_xor(zs[o], m);
            zq[o] += __shfl_xor(zq[o], m);
        }
    }
    int wave = t >> 6, lane = t & 63;
    if (lane == 0) {
        #pragma unroll
        for (int o = 0; o < 16; o++) {
            red[wave][o] = zs[o];
            red[wave][16 + o] = zq[o];
        }
    }
    __syncthreads();
    if (t < 32)
        atomicAdd(&bnstat[t], red[0][t] + red[1][t] + red[2][t] + red[3][t]);
}

__device__ __forceinline__ void store_zh(__half* __restrict__ zh, int n, float zv[16]) {
    __half2 p[8];
    #pragma unroll
    for (int j = 0; j < 8; j++) p[j] = __floats2half2_rn(zv[2 * j], zv[2 * j + 1]);
    *(uint4*)(zh + n * DIM) = *(uint4*)&p[0];
    *(uint4*)(zh + n * DIM + 8) = *(uint4*)&p[4];
}

__global__ void __launch_bounds__(256) k_mlp1(
    const float* __restrict__ h,
    const float* __restrict__ W1, const float* __restrict__ b1,
    const float* __restrict__ W2, const float* __restrict__ b2,
    __half* __restrict__ zh, float* __restrict__ bnstat) {
    __shared__ float W1s[NFP * 16], W2s[256], b1s[16], b2s[16];
    int t = threadIdx.x;
    for (int j = t; j < NFP * 16; j += 256) W1s[j] = W1[j];
    W2s[t] = W2[t];
    if (t < 16) { b1s[t] = b1[t]; b2s[t] = b2[t]; }
    __syncthreads();
    int n = blockIdx.x * 256 + t;
    bool active = n < N_NODES;
    float zv[16];
    if (active) {
        float hv[NFP];
        #pragma unroll
        for (int j = 0; j < 8; j++) {
            float4 v = *(const float4*)(h + n * H1STR + j * 4);
            hv[j * 4] = v.x; hv[j * 4 + 1] = v.y; hv[j * 4 + 2] = v.z; hv[j * 4 + 3] = v.w;
        }
        hv[32] = h[n * H1STR + 32];
        float tv[16];
        #pragma unroll
        for (int o = 0; o < 16; o++) {
            float s = b1s[o];
            #pragma unroll
            for (int f = 0; f < NFP; f++) s += hv[f] * W1s[f * 16 + o];
            tv[o] = fmaxf(s, 0.f);
        }
        #pragma unroll
        for (int o = 0; o < 16; o++) {
            float s = b2s[o];
            #pragma unroll
            for (int f = 0; f < 16; f++) s += tv[f] * W2s[f * 16 + o];
            zv[o] = fmaxf(s, 0.f);
        }
        store_zh(zh, n, zv);
    }
    mlp_bn_tail(zv, active, t, bnstat);
}

// ---------------- pooling with BN folded in ----------------
__global__ void __launch_bounds__(256) k_pool(const __half* __restrict__ zh,
                                              const int* __restrict__ batch,
                                              const float* __restrict__ bnstat,
                                              const float* __restrict__ gamma,
                                              const float* __restrict__ beta,
                                              float* __restrict__ gsum,
                                              float* __restrict__ gcnt) {
    __shared__ float lsum[BGR * DIM];
    __shared__ float lcnt[BGR];
    int t = threadIdx.x;
    for (int j = t; j < BGR * DIM; j += 256) lsum[j] = 0.f;
    if (t < BGR) lcnt[t] = 0.f;
    __syncthreads();
    int f = t & 15, r = t >> 4;
    const float invn = 1.f / (float)N_NODES;
    float mu = bnstat[f] * invn;
    float var = bnstat[DIM + f] * invn - mu * mu;
    float sc = gamma[f] * rsqrtf(var + BN_EPSV);
    float sh = beta[f] - mu * sc;
    int start = blockIdx.x * POOL_CHUNK;
    float acc = 0.f, cacc = 0.f;
    int cur = -1;
    for (int i = 0; i < POOL_CHUNK / 16; i++) {
        int n = start + r + i * 16;
        if (n >= N_NODES) break;
        int b = batch[n];
        if (b != cur) {
            if (cur >= 0) {
                atomicAdd(&lsum[cur * DIM + f], acc);
                if (f == 0) atomicAdd(&lcnt[cur], cacc);
            }
            cur = b; acc = 0.f; cacc = 0.f;
        }
        acc += fmaf(__half2float(zh[n * DIM + f]), sc, sh);
        cacc += 1.f;
    }
    if (cur >= 0) {
        atomicAdd(&lsum[cur * DIM + f], acc);
        if (f == 0) atomicAdd(&lcnt[cur], cacc);
    }
    __syncthreads();
    for (int j = t; j < BGR * DIM; j += 256) {
        float v = lsum[j];
        if (v != 0.f) atomicAdd(&gsum[j], v);
    }
    if (t < BGR) {
        float v = lcnt[t];
        if (v != 0.f) atomicAdd(&gcnt[t], v);
    }
}

// ---------------- RNA: merged wsum ----------------
__global__ void __launch_bounds__(256) k_wsum(const int* __restrict__ blg,
                                              const int* __restrict__ bpg,
                                              const int* __restrict__ bll,
                                              const int* __restrict__ bpl,
                                              const float* __restrict__ cwTg,
                                              const float* __restrict__ cwTl,
                                              float* __restrict__ Wp,
                                              float* __restrict__ Wlocal) {
    int b = blockIdx.x, y = blockIdx.y;
    int t = threadIdx.x;
    if (y < 40) {
        int v = y >> 3, seg = y & 7;
        int s = bpg[b * 6 + v], e = bpg[b * 6 + v + 1];
        int cnt = e - s;
        int chunk = (cnt + SEG_G - 1) / SEG_G;
        int j0 = s + seg * chunk;
        int j1 = j0 + chunk; if (j1 > e) j1 = e;
        const int* bl = blg + b * MAXLEN;
        float acc = 0.f;
        int j = j0;
        while (j + 3 < j1) {
            int t0 = bl[j], t1 = bl[j + 1], t2 = bl[j + 2], t3 = bl[j + 3];
            float a0 = cwTg[t0 * 256 + t];
            float a1 = cwTg[t1 * 256 + t];
            float a2 = cwTg[t2 * 256 + t];
            float a3 = cwTg[t3 * 256 + t];
            acc += a0 + a1 + a2 + a3;
            j += 4;
        }
        while (j < j1) {
            acc += cwTg[bl[j] * 256 + t];
            j++;
        }
        Wp[((b * 5 + v) * SEG_G + seg) * 256 + t] = acc;
    } else {
        int v = y - 40;
        int s = bpl[b * 66 + v], e = bpl[b * 66 + v + 1];
        const int* bl = bll + b * LOCLEN;
        float acc = 0.f;
        int j = s;
        while (j + 3 < e) {
            int t0 = bl[j], t1 = bl[j + 1], t2 = bl[j + 2], t3 = bl[j + 3];
            float a0 = cwTl[t0 * 256 + t];
            float a1 = cwTl[t1 * 256 + t];
            float a2 = cwTl[t2 * 256 + t];
            float a3 = cwTl[t3 * 256 + t];
            acc += a0 + a1 + a2 + a3;
            j += 4;
        }
        while (j < e) {
            acc += cwTl[bl[j] * 256 + t];
            j++;
        }
        int o = t >> 3, k = t & 7;
        Wlocal[((b * NF + o) * 65 + v) * KS + k] = acc;
    }
}

// fused y + fcpart
__global__ void __launch_bounds__(128) k_yfc(const float* __restrict__ Wpg,
                                             const float* __restrict__ Wl,
                                             const float* __restrict__ emb1,
                                             const float* __restrict__ emb2,
                                             const float* __restrict__ cb1,
                                             const float* __restrict__ cb2,
                                             const float* __restrict__ w,
                                             float* __restrict__ partial) {
    int which = blockIdx.y;
    int bo = blockIdx.x;
    int b = bo >> 5, o = bo & 31;
    int t = threadIdx.x;  // 128
    const float* emb = which ? emb2 : emb1;
    const float* cb = which ? cb2 : cb1;
    int V = which ? 65 : 5;
    __shared__ float Wsh[65 * KS];
    __shared__ float ych[OUTT];
    if (which) {
        const float* Wrow = Wl + (b * NF + o) * 65 * KS;
        for (int j = t; j < 65 * KS; j += 128) Wsh[j] = Wrow[j];
    } else {
        for (int j = t; j < 5 * KS; j += 128) {
            int v = j >> 3, k = j & 7;
            const float* p = Wpg + (b * 5 + v) * SEG_G * 256 + o * 8 + k;
            float s = 0.f;
            #pragma unroll
            for (int g = 0; g < SEG_G; g++) s += p[g * 256];
            Wsh[j] = s;
        }
    }
    __syncthreads();
    if (t < OUTT) {
        float acc = cb[o];
        for (int v = 0; v < V; v++) {
            const float* ep = emb + v * EMB + t;
            #pragma unroll
            for (int k = 0; k < KS; k++) acc += Wsh[v * KS + k] * ep[k];
        }
        ych[t] = acc;
    }
    __syncthreads();
    float facc = 0.f;
    const float* wp = w + (o * OUTT) * EMB + t;
    #pragma unroll 4
    for (int jj = 0; jj < OUTT; jj++) facc += ych[jj] * wp[jj * EMB];
    partial[((which * BGR + b) * NKC + o) * EMB + t] = facc;
}

// merged fcred + xp (final outputs)
__global__ void __launch_bounds__(128) k_tail(const float* __restrict__ partial,
                                              const float* __restrict__ bias,
                                              const float* __restrict__ gsum,
                                              const float* __restrict__ gcnt,
                                              const float* __restrict__ w,
                                              const float* __restrict__ xpb,
                                              float* __restrict__ out) {
    int b = blockIdx.x;
    int e = threadIdx.x;
    if (blockIdx.y == 0) {
        const float* pg = partial + b * NKC * EMB + e;
        const float* pl = partial + (BGR + b) * NKC * EMB + e;
        float ag = bias[e], al = bias[e];
        #pragma unroll
        for (int k = 0; k < NKC; k++) { ag += pg[k * EMB]; al += pl[k * EMB]; }
        out[b * EMB + e] = 0.5f * (ag + al);
    } else {
        float inv = 1.f / fmaxf(gcnt[b], 1.f);
        float acc = xpb[e];
        #pragma unroll
        for (int f = 0; f < DIM; f++) acc += gsum[b * DIM + f] * inv * w[f * EMB + e];
        out[BGR * EMB + b * EMB + e] = fmaxf(acc, 0.f);
    }
}

extern "C" void kernel_launch(void* const* d_in, const int* in_sizes, int n_in,
                              void* d_out, int out_size, void* d_ws, size_t ws_size,
                              hipStream_t stream) {
    const float* pro_x = (const float*)d_in[0];
    const int* eidx = (const int*)d_in[1];
    const int* esrc = eidx;
    const int* edst = eidx + N_EDGES;
    const float* pw = (const float*)d_in[2];
    const int* batch = (const int*)d_in[3];
    const int* rg = (const int*)d_in[4];
    const int* rl = (const int*)d_in[5];
    const float* g1_w1 = (const float*)d_in[6];
    const float* g1_b1 = (const float*)d_in[7];
    const float* g1_w2 = (const float*)d_in[8];
    const float* g1_b2 = (const float*)d_in[9];
    const float* g1_ew = (const float*)d_in[10];
    const float* g1_eb = (const float*)d_in[11];
    const float* g1_eps = (const float*)d_in[12];
    const float* g_w1 = (const float*)d_in[13];
    const float* g_b1 = (const float*)d_in[14];
    const float* g_w2 = (const float*)d_in[15];
    const float* g_b2 = (const float*)d_in[16];
    const float* g_ew = (const float*)d_in[17];
    const float* g_eb = (const float*)d_in[18];
    const float* g_eps = (const float*)d_in[19];
    const float* bn_gamma = (const float*)d_in[20];
    const float* bn_beta = (const float*)d_in[21];
    const float* fc1_xp_w = (const float*)d_in[22];
    const float* fc1_xp_b = (const float*)d_in[23];
    const float* emb1 = (const float*)d_in[24];
    const float* emb2 = (const float*)d_in[25];
    const float* convr1_w = (const float*)d_in[26];
    const float* convr1_b = (const float*)d_in[27];
    const float* convr2_w = (const float*)d_in[28];
    const float* convr2_b = (const float*)d_in[29];
    const float* fcxr_w = (const float*)d_in[30];
    const float* fcxr_b = (const float*)d_in[31];
    float* out = (float*)d_out;

    // persistent buffers
    float* wsf = (float*)d_ws;
    int* ptr       = (int*)wsf;        wsf += 100128;
    int* binoff    = (int*)wsf;        wsf += 512;
    int* bincur    = (int*)wsf;        wsf += 512;
    unsigned* er   = (unsigned*)wsf;   wsf += 2 * N_EDGES;
    float* stats   = wsf;              wsf += 1280;
    // union region lifetimes:
    //   tmp_sw/bh die after part2; cwT/W* die after yfc; blists/bptrs die after wsum;
    //   fcpart (un+6600000..7124288, over dead blists) lives k_yfc -> k_tail, ends
    //   BEFORE h (7400000) so the GNN stack cannot clobber it [round-9 bugfix];
    //   h dies after mlp1; zhB (10200000..11000000) overlaps only dead h-tail.
    float* un = wsf;
    int2* tmp_sw = (int2*)un;                    // 0 .. 6400000
    int* bh      = (int*)(un + 7200000);         // 7200000 .. 7400192
    float* cwTg  = un;                           // 0 .. 768000   (after part2)
    float* cwTl  = un + 768000;                  // .. 1535488
    __half* zhA  = (__half*)(un + 1600000);      // .. 2400000
    __half* xh1  = (__half*)(un + 2400000);      // .. 4000000
    __half* xh32 = (__half*)(un + 4000000);      // .. 4050000
    float* Wpg   = un + 4300000;                 // .. 4955360
    float* Wl    = un + 5000000;                 // .. 6064960
    int* blg     = (int*)(un + 6600000);         // .. 6792000 (dies after wsum)
    int* bll     = (int*)(un + 6800000);         // .. 6991872 (dies after wsum)
    int* bpg     = (int*)(un + 7000000);         // .. 7000384 (dies after wsum)
    int* bpl     = (int*)(un + 7001000);         // .. 7005224 (dies after wsum)
    float* fcpart = un + 6600000;                // .. 7124288 (yfc -> tail; < h start)
    float* h      = un + 7400000;                // .. 11000000 (dies after mlp1)
    __half* zhB  = (__half*)(un + 10200000);     // .. 11000000 (after h dead)
    float* gsum   = stats;
    float* gcnt   = stats + 1024;
    float* bnstat = stats + 1088;

    hipMemsetAsync(stats, 0, 1280 * sizeof(float), stream);

    // CSR build + RNA bucketing (merged independent work)
    k_pre1<<<BCNT_BLK + 128, 256, 0, stream>>>(edst, bh, rg, rl, blg, bpg, bll, bpl);
    k_binscan<<<1, 512, 0, stream>>>(bh, binoff, bincur);
    k_part1<<<P1_BLOCKS, 256, 0, stream>>>(esrc, edst, pw, bincur, tmp_sw);
    k_part2<<<NBIN, 256, 0, stream>>>(tmp_sw, binoff, er, ptr);

    // conv weight transpose + pro_x fp16 (both overwrite dead tmp_sw region)
    k_pre2<<<MAXLEN + LOCLEN + (N_NODES * NFP + 255) / 256, 256, 0, stream>>>(
        convr1_w, convr2_w, cwTg, cwTl, pro_x, xh1, xh32);

    // RNA branch
    k_wsum<<<dim3(BGR, 105), 256, 0, stream>>>(blg, bpg, bll, bpl, cwTg, cwTl, Wpg, Wl);
    k_yfc<<<dim3(BGR * NF, 2), 128, 0, stream>>>(Wpg, Wl, emb1, emb2, convr1_b, convr2_b,
                                                 fcxr_w, fcpart);

    // GNN stack
    k_agg1<<<AGGB1, 256, 0, stream>>>(xh1, xh32, ptr, er, g1_ew, g1_eb, g1_eps, h);
    k_mlp1<<<MLPB, 256, 0, stream>>>(h, g1_w1, g1_b1, g1_w2, g1_b2, zhA, bnstat);
    {
        __half* zi[5] = {zhA, zhB, zhA, zhB, zhA};
        for (int i = 0; i < 4; i++) {
            k_f16<<<AGGB16, 256, 0, stream>>>(zi[i], ptr, er,
                                              g_ew + i * DIM, g_eb + i * DIM, g_eps + i,
                                              bnstat + i * 32, bn_gamma + i * DIM,
                                              bn_beta + i * DIM,
                                              g_w1 + i * DIM * DIM, g_b1 + i * DIM,
                                              g_w2 + i * DIM * DIM, g_b2 + i * DIM,
                                              zi[i + 1], bnstat + (i + 1) * 32);
        }
    }
    k_pool<<<POOL_BLKS, 256, 0, stream>>>(zhA, batch, bnstat + 4 * 32,
                                          bn_gamma + 4 * DIM, bn_beta + 4 * DIM, gsum, gcnt);
    // final outputs (fcred + xp merged; fcpart intact below h)
    k_tail<<<dim3(BGR, 2), 128, 0, stream>>>(fcpart, fcxr_b, gsum, gcnt,
                                             fc1_xp_w, fc1_xp_b, out);
}

// Round 11
// 559.490 us; speedup vs baseline: 1.1570x; 1.1570x over previous
//
#include <hip/hip_runtime.h>
#include <hip/hip_fp16.h>

#define N_NODES 100000
#define N_EDGES 3200000
#define BGR 64
#define DIM 16
#define NFP 33
#define ROW1 32
#define H1STR 36
#define EMB 128
#define MAXLEN 3000
#define LOCLEN 2998
#define NF 32
#define KS 8
#define OUTT 121
#define FC_IN 3872
#define BN_EPSV 1e-5f
#define POOL_CHUNK 256
#define POOL_BLKS 391
#define MLPB 391
#define AGGB1 6250
#define AGGB16 3125
// binned CSR build
#define NBIN 391
#define BCNT_BLK 512
#define P1_CHUNK 4096
#define P1_BLOCKS 782
#define MAXBIN 9088
// fc K-split
#define NKC 32
#define KCH 121
#define WDEC (1.f / 32767.f)
#define SEG_G 8

// ---------------- merged bincnt + bucket (independent preprocessing) ----------------
__global__ void __launch_bounds__(256) k_pre1(const int* __restrict__ dst,
                                              int* __restrict__ bh,
                                              const int* __restrict__ rg,
                                              const int* __restrict__ rl,
                                              int* __restrict__ blg, int* __restrict__ bpg,
                                              int* __restrict__ bll, int* __restrict__ bpl) {
    __shared__ int sh[NBIN];
    int t = threadIdx.x, bid = blockIdx.x;
    if (bid < BCNT_BLK) {
        for (int b = t; b < NBIN; b += 256) sh[b] = 0;
        __syncthreads();
        int e0 = bid * (N_EDGES / BCNT_BLK);
        int e1 = e0 + (N_EDGES / BCNT_BLK);
        for (int e = e0 + t; e < e1; e += 256) atomicAdd(&sh[dst[e] >> 8], 1);
        __syncthreads();
        for (int b = t; b < NBIN; b += 256) bh[b * BCNT_BLK + bid] = sh[b];
    } else {
        int idx = bid - BCNT_BLK;
        int which = idx >> 6, b = idx & 63;
        const int* tok = which ? rl : rg;
        int L = which ? LOCLEN : MAXLEN;
        int V = which ? 65 : 5;
        int* blist = which ? bll : blg;
        int* bptr = which ? bpl : bpg;
        int* hist = sh;
        int* cursor = sh + 70;
        if (t < V) hist[t] = 0;
        __syncthreads();
        for (int l = t; l < L; l += 256) atomicAdd(&hist[tok[b * L + l]], 1);
        __syncthreads();
        if (t == 0) {
            int run = 0;
            for (int v = 0; v < V; v++) {
                cursor[v] = run;
                bptr[b * (V + 1) + v] = run;
                run += hist[v];
            }
            bptr[b * (V + 1) + V] = run;
        }
        __syncthreads();
        for (int l = t; l < L; l += 256) {
            int v = tok[b * L + l];
            int p = atomicAdd(&cursor[v], 1);
            blist[b * L + p] = l;
        }
    }
}

__global__ void __launch_bounds__(512) k_binscan(const int* __restrict__ bh,
                                                 int* __restrict__ binoff,
                                                 int* __restrict__ bincur) {
    __shared__ int sc[512];
    int t = threadIdx.x;
    int s = 0;
    if (t < NBIN) {
        const int4* row = (const int4*)(bh + t * BCNT_BLK);
        #pragma unroll 4
        for (int k = 0; k < BCNT_BLK / 4; k++) {
            int4 v = row[k];
            s += v.x + v.y + v.z + v.w;
        }
    }
    sc[t] = s;
    __syncthreads();
    for (int off = 1; off < 512; off <<= 1) {
        int v = (t >= off) ? sc[t - off] : 0;
        __syncthreads();
        sc[t] += v;
        __syncthreads();
    }
    int excl = sc[t] - s;
    if (t <= NBIN) binoff[t] = excl;
    if (t < NBIN) bincur[t] = excl;
}

// pass 1: single coalesced read -> LDS-staged records -> LDS rank -> coalesced write.
__global__ void __launch_bounds__(256) k_part1(const int* __restrict__ src,
                                               const int* __restrict__ dst,
                                               const float* __restrict__ w,
                                               int* __restrict__ bincur,
                                               int2* __restrict__ tmp_sw) {
    __shared__ int2 srec[P1_CHUNK];
    __shared__ unsigned short sbin[P1_CHUNK];
    __shared__ unsigned short sperm[P1_CHUNK];
    __shared__ int hist[NBIN];
    __shared__ int off[NBIN];
    __shared__ int cur[NBIN];
    __shared__ int base[NBIN];
    __shared__ int sc[512];
    int t = threadIdx.x;
    int g0 = blockIdx.x * P1_CHUNK;
    int cn = N_EDGES - g0; if (cn > P1_CHUNK) cn = P1_CHUNK;
    for (int b = t; b < NBIN; b += 256) hist[b] = 0;
    __syncthreads();
    for (int j = t; j < cn; j += 256) {
        int d = dst[g0 + j];
        int b = d >> 8;
        sbin[j] = (unsigned short)b;
        srec[j] = make_int2(src[g0 + j] | ((d & 255) << 20), __float_as_int(w[g0 + j]));
        atomicAdd(&hist[b], 1);
    }
    __syncthreads();
    sc[t] = (t < NBIN) ? hist[t] : 0;
    sc[256 + t] = (256 + t < NBIN) ? hist[256 + t] : 0;
    __syncthreads();
    for (int o = 1; o <= 256; o <<= 1) {
        int v0 = (t >= o) ? sc[t - o] : 0;
        int v1 = sc[256 + t - o];
        __syncthreads();
        sc[t] += v0;
        sc[256 + t] += v1;
        __syncthreads();
    }
    for (int b = t; b < NBIN; b += 256) {
        int e = sc[b] - hist[b];
        off[b] = e;
        cur[b] = e;
        int c = hist[b];
        base[b] = c ? atomicAdd(&bincur[b], c) : 0;
    }
    __syncthreads();
    for (int j = t; j < cn; j += 256) {
        int p = atomicAdd(&cur[sbin[j]], 1);
        sperm[p] = (unsigned short)j;
    }
    __syncthreads();
    for (int p = t; p < cn; p += 256) {
        int j = sperm[p];
        int b = sbin[j];
        tmp_sw[base[b] + (p - off[b])] = srec[j];
    }
}

// pass 2: per-bin fine sort + ptr; emit compact 4B edge records src(17) | wq(15)
__global__ void __launch_bounds__(256) k_part2(const int2* __restrict__ tmp_sw,
                                               const int* __restrict__ binoff,
                                               unsigned* __restrict__ er,
                                               int* __restrict__ ptr) {
    __shared__ unsigned char sdl[MAXBIN];
    __shared__ unsigned short perm[MAXBIN];
    __shared__ int hist[256];
    __shared__ int cur[256];
    __shared__ int sc[256];
    int t = threadIdx.x, b = blockIdx.x;
    int nlo = b << 8;
    int e0 = binoff[b], e1 = binoff[b + 1];
    int cnt = e1 - e0;
    int stage = cnt < MAXBIN ? cnt : MAXBIN;
    hist[t] = 0;
    __syncthreads();
    for (int j = t; j < stage; j += 256) {
        unsigned char dl = (unsigned char)((tmp_sw[e0 + j].x >> 20) & 255);
        sdl[j] = dl;
        atomicAdd(&hist[dl], 1);
    }
    for (int j = stage + t; j < cnt; j += 256)
        atomicAdd(&hist[(tmp_sw[e0 + j].x >> 20) & 255], 1);
    __syncthreads();
    int v = hist[t];
    sc[t] = v;
    __syncthreads();
    for (int off = 1; off < 256; off <<= 1) {
        int u = (t >= off) ? sc[t - off] : 0;
        __syncthreads();
        sc[t] += u;
        __syncthreads();
    }
    int excl = sc[t] - v;
    cur[t] = excl;
    if (nlo + t < N_NODES) ptr[nlo + t] = e0 + excl;
    if (b == NBIN - 1 && t == 0) ptr[N_NODES] = N_EDGES;
    __syncthreads();
    for (int j = t; j < stage; j += 256) {
        int p = atomicAdd(&cur[sdl[j]], 1);
        perm[p] = (unsigned short)j;
    }
    __syncthreads();
    for (int j = stage + t; j < cnt; j += 256) {
        int2 sw = tmp_sw[e0 + j];
        int p = atomicAdd(&cur[(sw.x >> 20) & 255], 1);
        unsigned wq = (unsigned)(__int_as_float(sw.y) * 32767.f + 0.5f);
        er[e0 + p] = ((unsigned)sw.x & 0x1FFFFu) | (wq << 17);
    }
    for (int p = t; p < stage; p += 256) {
        int2 sw = tmp_sw[e0 + perm[p]];
        unsigned wq = (unsigned)(__int_as_float(sw.y) * 32767.f + 0.5f);
        er[e0 + p] = ((unsigned)sw.x & 0x1FFFFu) | (wq << 17);
    }
}

// ---------------- merged conv-weight transpose + pro_x fp16 conversion ----------------
__global__ void __launch_bounds__(256) k_pre2(const float* __restrict__ cw1,
                                              const float* __restrict__ cw2,
                                              float* __restrict__ cwTg,
                                              float* __restrict__ cwTl,
                                              const float* __restrict__ x,
                                              __half* __restrict__ xh,
                                              __half* __restrict__ xh32) {
    int bid = blockIdx.x, t = threadIdx.x;
    if (bid < MAXLEN) {
        cwTg[bid * 256 + t] = cw1[(t >> 3) * (MAXLEN * KS) + bid * KS + (t & 7)];
    } else if (bid < MAXLEN + LOCLEN) {
        int ll = bid - MAXLEN;
        cwTl[ll * 256 + t] = cw2[(t >> 3) * (LOCLEN * KS) + ll * KS + (t & 7)];
    } else {
        int i = (bid - (MAXLEN + LOCLEN)) * 256 + t;
        if (i < N_NODES * NFP) {
            int n = i / NFP, f = i - n * NFP;
            __half v = __float2half(x[i]);
            if (f < 32) xh[n * ROW1 + f] = v;
            else xh32[n] = v;
        }
    }
}

// 8-feature accumulate helpers
__device__ __forceinline__ void acc8p(float a[8], uint4 r, float wv,
                                      const float* __restrict__ ewf,
                                      const float* __restrict__ ebf) {
    float2 f01 = __half22float2(*(__half2*)&r.x);
    float2 f23 = __half22float2(*(__half2*)&r.y);
    float2 f45 = __half22float2(*(__half2*)&r.z);
    float2 f67 = __half22float2(*(__half2*)&r.w);
    float x[8] = {f01.x, f01.y, f23.x, f23.y, f45.x, f45.y, f67.x, f67.y};
    #pragma unroll
    for (int j = 0; j < 8; j++)
        a[j] += fmaxf(x[j] + fmaf(wv, ewf[j], ebf[j]), 0.f);
}

__device__ __forceinline__ void acc8s(float a[8], uint4 r, float wv,
                                      const float* __restrict__ scf,
                                      const float* __restrict__ cbf,
                                      const float* __restrict__ ewf) {
    float2 f01 = __half22float2(*(__half2*)&r.x);
    float2 f23 = __half22float2(*(__half2*)&r.y);
    float2 f45 = __half22float2(*(__half2*)&r.z);
    float2 f67 = __half22float2(*(__half2*)&r.w);
    float x[8] = {f01.x, f01.y, f23.x, f23.y, f45.x, f45.y, f67.x, f67.y};
    #pragma unroll
    for (int j = 0; j < 8; j++)
        a[j] += fmaxf(fmaf(x[j], scf[j], fmaf(wv, ewf[j], cbf[j])), 0.f);
}

// ---------------- layer-1 aggregate (33 feats) [round-8 proven, unchanged] ----------------
__global__ void __launch_bounds__(256) k_agg1(
    const __half* __restrict__ xh, const __half* __restrict__ xh32,
    const int* __restrict__ ptr, const unsigned* __restrict__ er,
    const float* __restrict__ ew, const float* __restrict__ ebv,
    const float* __restrict__ epsp, float* __restrict__ h) {
    int t = threadIdx.x;
    int wave = t >> 6, lane = t & 63;
    int nl = lane >> 4;
    int slot = (lane >> 2) & 3;
    int q = lane & 3;
    float ewf[8], ebf[8];
    #pragma unroll
    for (int j = 0; j < 8; j++) { ewf[j] = ew[q * 8 + j]; ebf[j] = ebv[q * 8 + j]; }
    float ew32 = ew[32], eb32 = ebv[32];
    float ep = 1.f + epsp[0];
    int node = blockIdx.x * 16 + wave * 4 + nl;
    int e0 = ptr[node], e1 = ptr[node + 1];
    float a[8] = {0, 0, 0, 0, 0, 0, 0, 0};
    float a32 = 0.f;
    int i = e0 + slot;
    while (i + 4 < e1) {
        unsigned ev0 = er[i];
        unsigned ev1 = er[i + 4];
        int s0 = ev0 & 0x1FFFF, s1 = ev1 & 0x1FFFF;
        float wv0 = (float)(ev0 >> 17) * WDEC;
        float wv1 = (float)(ev1 >> 17) * WDEC;
        uint4 r0 = *(const uint4*)(xh + s0 * ROW1 + q * 8);
        uint4 r1 = *(const uint4*)(xh + s1 * ROW1 + q * 8);
        acc8p(a, r0, wv0, ewf, ebf);
        acc8p(a, r1, wv1, ewf, ebf);
        if (q == 0) {
            a32 += fmaxf(__half2float(xh32[s0]) + fmaf(wv0, ew32, eb32), 0.f);
            a32 += fmaxf(__half2float(xh32[s1]) + fmaf(wv1, ew32, eb32), 0.f);
        }
        i += 8;
    }
    if (i < e1) {
        unsigned ev = er[i];
        int s = ev & 0x1FFFF;
        float wv = (float)(ev >> 17) * WDEC;
        uint4 r = *(const uint4*)(xh + s * ROW1 + q * 8);
        acc8p(a, r, wv, ewf, ebf);
        if (q == 0)
            a32 += fmaxf(__half2float(xh32[s]) + fmaf(wv, ew32, eb32), 0.f);
    }
    #pragma unroll
    for (int j = 0; j < 8; j++) {
        a[j] += __shfl_xor(a[j], 4);
        a[j] += __shfl_xor(a[j], 8);
    }
    a32 += __shfl_xor(a32, 4);
    a32 += __shfl_xor(a32, 8);
    if (slot == 0) {
        uint4 sraw = *(const uint4*)(xh + node * ROW1 + q * 8);
        float2 s01 = __half22float2(*(__half2*)&sraw.x);
        float2 s23 = __half22float2(*(__half2*)&sraw.y);
        float2 s45 = __half22float2(*(__half2*)&sraw.z);
        float2 s67 = __half22float2(*(__half2*)&sraw.w);
        float* hp = h + node * H1STR + q * 8;
        *(float4*)hp = make_float4(ep * s01.x + a[0], ep * s01.y + a[1],
                                   ep * s23.x + a[2], ep * s23.y + a[3]);
        *(float4*)(hp + 4) = make_float4(ep * s45.x + a[4], ep * s45.y + a[5],
                                         ep * s67.x + a[6], ep * s67.y + a[7]);
        if (q == 0)
            h[node * H1STR + 32] = ep * __half2float(xh32[node]) + a32;
    }
}

// ---------------- layer 2-5 aggregate (16 feats), BN folded [round-8 proven] ----------------
__global__ void __launch_bounds__(256) k_agg16(
    const __half* __restrict__ zh, const int* __restrict__ ptr,
    const unsigned* __restrict__ er,
    const float* __restrict__ ew, const float* __restrict__ ebv,
    const float* __restrict__ epsp,
    const float* __restrict__ bnstat, const float* __restrict__ gamma,
    const float* __restrict__ beta, float* __restrict__ h) {
    int t = threadIdx.x;
    int wave = t >> 6, lane = t & 63;
    int nl = lane >> 3;
    int slot = (lane >> 1) & 3;
    int hh = lane & 1;
    float ep = 1.f + epsp[0];
    const float invn = 1.f / (float)N_NODES;
    float scf[8], shf[8], cbf[8], ewf[8];
    #pragma unroll
    for (int j = 0; j < 8; j++) {
        int f = hh * 8 + j;
        float mu = bnstat[f] * invn;
        float var = bnstat[DIM + f] * invn - mu * mu;
        float sc = gamma[f] * rsqrtf(var + BN_EPSV);
        scf[j] = sc;
        shf[j] = beta[f] - mu * sc;
        cbf[j] = shf[j] + ebv[f];
        ewf[j] = ew[f];
    }
    int node = blockIdx.x * 32 + wave * 8 + nl;
    int e0 = ptr[node], e1 = ptr[node + 1];
    float a[8] = {0, 0, 0, 0, 0, 0, 0, 0};
    int i = e0 + slot;
    while (i + 4 < e1) {
        unsigned ev0 = er[i];
        unsigned ev1 = er[i + 4];
        float wv0 = (float)(ev0 >> 17) * WDEC;
        float wv1 = (float)(ev1 >> 17) * WDEC;
        uint4 r0 = *(const uint4*)(zh + (ev0 & 0x1FFFFu) * DIM + hh * 8);
        uint4 r1 = *(const uint4*)(zh + (ev1 & 0x1FFFFu) * DIM + hh * 8);
        acc8s(a, r0, wv0, scf, cbf, ewf);
        acc8s(a, r1, wv1, scf, cbf, ewf);
        i += 8;
    }
    if (i < e1) {
        unsigned ev = er[i];
        float wv = (float)(ev >> 17) * WDEC;
        uint4 r = *(const uint4*)(zh + (ev & 0x1FFFFu) * DIM + hh * 8);
        acc8s(a, r, wv, scf, cbf, ewf);
    }
    #pragma unroll
    for (int j = 0; j < 8; j++) a[j] += __shfl_xor(a[j], 2);
    #pragma unroll
    for (int j = 0; j < 8; j++) a[j] += __shfl_xor(a[j], 4);
    if (slot == 0) {
        uint4 sraw = *(const uint4*)(zh + node * DIM + hh * 8);
        float2 s01 = __half22float2(*(__half2*)&sraw.x);
        float2 s23 = __half22float2(*(__half2*)&sraw.y);
        float2 s45 = __half22float2(*(__half2*)&sraw.z);
        float2 s67 = __half22float2(*(__half2*)&sraw.w);
        float xs[8] = {s01.x, s01.y, s23.x, s23.y, s45.x, s45.y, s67.x, s67.y};
        float o8[8];
        #pragma unroll
        for (int j = 0; j < 8; j++)
            o8[j] = ep * fmaf(xs[j], scf[j], shf[j]) + a[j];
        float* hp = h + node * DIM + hh * 8;
        *(float4*)hp = make_float4(o8[0], o8[1], o8[2], o8[3]);
        *(float4*)(hp + 4) = make_float4(o8[4], o8[5], o8[6], o8[7]);
    }
}

// ---------------- fused per-thread MLP + shfl-reduced BN partials -> atomic bnstat ----------------
__device__ __forceinline__ void mlp_bn_tail(float zv[16], bool active, int t,
                                            float* __restrict__ bnstat) {
    __shared__ float red[4][32];
    float zs[16], zq[16];
    #pragma unroll
    for (int o = 0; o < 16; o++) {
        zs[o] = active ? zv[o] : 0.f;
        zq[o] = active ? zv[o] * zv[o] : 0.f;
    }
    #pragma unroll
    for (int m = 1; m <= 32; m <<= 1) {
        #pragma unroll
        for (int o = 0; o < 16; o++) {
            zs[o] += __shfl_xor(zs[o], m);
            zq[o] += __shfl_xor(zq[o], m);
        }
    }
    int wave = t >> 6, lane = t & 63;
    if (lane == 0) {
        #pragma unroll
        for (int o = 0; o < 16; o++) {
            red[wave][o] = zs[o];
            red[wave][16 + o] = zq[o];
        }
    }
    __syncthreads();
    if (t < 32)
        atomicAdd(&bnstat[t], red[0][t] + red[1][t] + red[2][t] + red[3][t]);
}

__device__ __forceinline__ void store_zh(__half* __restrict__ zh, int n, float zv[16]) {
    __half2 p[8];
    #pragma unroll
    for (int j = 0; j < 8; j++) p[j] = __floats2half2_rn(zv[2 * j], zv[2 * j + 1]);
    *(uint4*)(zh + n * DIM) = *(uint4*)&p[0];
    *(uint4*)(zh + n * DIM + 8) = *(uint4*)&p[4];
}

__global__ void __launch_bounds__(256) k_mlp16(
    const float* __restrict__ h,
    const float* __restrict__ W1, const float* __restrict__ b1,
    const float* __restrict__ W2, const float* __restrict__ b2,
    __half* __restrict__ zh, float* __restrict__ bnstat) {
    __shared__ float W1s[256], W2s[256], b1s[16], b2s[16];
    int t = threadIdx.x;
    W1s[t] = W1[t];
    W2s[t] = W2[t];
    if (t < 16) { b1s[t] = b1[t]; b2s[t] = b2[t]; }
    __syncthreads();
    int n = blockIdx.x * 256 + t;
    bool active = n < N_NODES;
    float zv[16];
    if (active) {
        float hv[16];
        #pragma unroll
        for (int j = 0; j < 4; j++) {
            float4 v = *(const float4*)(h + n * DIM + j * 4);
            hv[j * 4] = v.x; hv[j * 4 + 1] = v.y; hv[j * 4 + 2] = v.z; hv[j * 4 + 3] = v.w;
        }
        float tv[16];
        #pragma unroll
        for (int o = 0; o < 16; o++) {
            float s = b1s[o];
            #pragma unroll
            for (int f = 0; f < 16; f++) s += hv[f] * W1s[f * 16 + o];
            tv[o] = fmaxf(s, 0.f);
        }
        #pragma unroll
        for (int o = 0; o < 16; o++) {
            float s = b2s[o];
            #pragma unroll
            for (int f = 0; f < 16; f++) s += tv[f] * W2s[f * 16 + o];
            zv[o] = fmaxf(s, 0.f);
        }
        store_zh(zh, n, zv);
    }
    mlp_bn_tail(zv, active, t, bnstat);
}

__global__ void __launch_bounds__(256) k_mlp1(
    const float* __restrict__ h,
    const float* __restrict__ W1, const float* __restrict__ b1,
    const float* __restrict__ W2, const float* __restrict__ b2,
    __half* __restrict__ zh, float* __restrict__ bnstat) {
    __shared__ float W1s[NFP * 16], W2s[256], b1s[16], b2s[16];
    int t = threadIdx.x;
    for (int j = t; j < NFP * 16; j += 256) W1s[j] = W1[j];
    W2s[t] = W2[t];
    if (t < 16) { b1s[t] = b1[t]; b2s[t] = b2[t]; }
    __syncthreads();
    int n = blockIdx.x * 256 + t;
    bool active = n < N_NODES;
    float zv[16];
    if (active) {
        float hv[NFP];
        #pragma unroll
        for (int j = 0; j < 8; j++) {
            float4 v = *(const float4*)(h + n * H1STR + j * 4);
            hv[j * 4] = v.x; hv[j * 4 + 1] = v.y; hv[j * 4 + 2] = v.z; hv[j * 4 + 3] = v.w;
        }
        hv[32] = h[n * H1STR + 32];
        float tv[16];
        #pragma unroll
        for (int o = 0; o < 16; o++) {
            float s = b1s[o];
            #pragma unroll
            for (int f = 0; f < NFP; f++) s += hv[f] * W1s[f * 16 + o];
            tv[o] = fmaxf(s, 0.f);
        }
        #pragma unroll
        for (int o = 0; o < 16; o++) {
            float s = b2s[o];
            #pragma unroll
            for (int f = 0; f < 16; f++) s += tv[f] * W2s[f * 16 + o];
            zv[o] = fmaxf(s, 0.f);
        }
        store_zh(zh, n, zv);
    }
    mlp_bn_tail(zv, active, t, bnstat);
}

// ---------------- pooling with BN folded in ----------------
__global__ void __launch_bounds__(256) k_pool(const __half* __restrict__ zh,
                                              const int* __restrict__ batch,
                                              const float* __restrict__ bnstat,
                                              const float* __restrict__ gamma,
                                              const float* __restrict__ beta,
                                              float* __restrict__ gsum,
                                              float* __restrict__ gcnt) {
    __shared__ float lsum[BGR * DIM];
    __shared__ float lcnt[BGR];
    int t = threadIdx.x;
    for (int j = t; j < BGR * DIM; j += 256) lsum[j] = 0.f;
    if (t < BGR) lcnt[t] = 0.f;
    __syncthreads();
    int f = t & 15, r = t >> 4;
    const float invn = 1.f / (float)N_NODES;
    float mu = bnstat[f] * invn;
    float var = bnstat[DIM + f] * invn - mu * mu;
    float sc = gamma[f] * rsqrtf(var + BN_EPSV);
    float sh = beta[f] - mu * sc;
    int start = blockIdx.x * POOL_CHUNK;
    float acc = 0.f, cacc = 0.f;
    int cur = -1;
    for (int i = 0; i < POOL_CHUNK / 16; i++) {
        int n = start + r + i * 16;
        if (n >= N_NODES) break;
        int b = batch[n];
        if (b != cur) {
            if (cur >= 0) {
                atomicAdd(&lsum[cur * DIM + f], acc);
                if (f == 0) atomicAdd(&lcnt[cur], cacc);
            }
            cur = b; acc = 0.f; cacc = 0.f;
        }
        acc += fmaf(__half2float(zh[n * DIM + f]), sc, sh);
        cacc += 1.f;
    }
    if (cur >= 0) {
        atomicAdd(&lsum[cur * DIM + f], acc);
        if (f == 0) atomicAdd(&lcnt[cur], cacc);
    }
    __syncthreads();
    for (int j = t; j < BGR * DIM; j += 256) {
        float v = lsum[j];
        if (v != 0.f) atomicAdd(&gsum[j], v);
    }
    if (t < BGR) {
        float v = lcnt[t];
        if (v != 0.f) atomicAdd(&gcnt[t], v);
    }
}

// ---------------- RNA: merged wsum ----------------
__global__ void __launch_bounds__(256) k_wsum(const int* __restrict__ blg,
                                              const int* __restrict__ bpg,
                                              const int* __restrict__ bll,
                                              const int* __restrict__ bpl,
                                              const float* __restrict__ cwTg,
                                              const float* __restrict__ cwTl,
                                              float* __restrict__ Wp,
                                              float* __restrict__ Wlocal) {
    int b = blockIdx.x, y = blockIdx.y;
    int t = threadIdx.x;
    if (y < 40) {
        int v = y >> 3, seg = y & 7;
        int s = bpg[b * 6 + v], e = bpg[b * 6 + v + 1];
        int cnt = e - s;
        int chunk = (cnt + SEG_G - 1) / SEG_G;
        int j0 = s + seg * chunk;
        int j1 = j0 + chunk; if (j1 > e) j1 = e;
        const int* bl = blg + b * MAXLEN;
        float acc = 0.f;
        int j = j0;
        while (j + 3 < j1) {
            int t0 = bl[j], t1 = bl[j + 1], t2 = bl[j + 2], t3 = bl[j + 3];
            float a0 = cwTg[t0 * 256 + t];
            float a1 = cwTg[t1 * 256 + t];
            float a2 = cwTg[t2 * 256 + t];
            float a3 = cwTg[t3 * 256 + t];
            acc += a0 + a1 + a2 + a3;
            j += 4;
        }
        while (j < j1) {
            acc += cwTg[bl[j] * 256 + t];
            j++;
        }
        Wp[((b * 5 + v) * SEG_G + seg) * 256 + t] = acc;
    } else {
        int v = y - 40;
        int s = bpl[b * 66 + v], e = bpl[b * 66 + v + 1];
        const int* bl = bll + b * LOCLEN;
        float acc = 0.f;
        int j = s;
        while (j + 3 < e) {
            int t0 = bl[j], t1 = bl[j + 1], t2 = bl[j + 2], t3 = bl[j + 3];
            float a0 = cwTl[t0 * 256 + t];
            float a1 = cwTl[t1 * 256 + t];
            float a2 = cwTl[t2 * 256 + t];
            float a3 = cwTl[t3 * 256 + t];
            acc += a0 + a1 + a2 + a3;
            j += 4;
        }
        while (j < e) {
            acc += cwTl[bl[j] * 256 + t];
            j++;
        }
        int o = t >> 3, k = t & 7;
        Wlocal[((b * NF + o) * 65 + v) * KS + k] = acc;
    }
}

// fused y + fcpart
__global__ void __launch_bounds__(128) k_yfc(const float* __restrict__ Wpg,
                                             const float* __restrict__ Wl,
                                             const float* __restrict__ emb1,
                                             const float* __restrict__ emb2,
                                             const float* __restrict__ cb1,
                                             const float* __restrict__ cb2,
                                             const float* __restrict__ w,
                                             float* __restrict__ partial) {
    int which = blockIdx.y;
    int bo = blockIdx.x;
    int b = bo >> 5, o = bo & 31;
    int t = threadIdx.x;  // 128
    const float* emb = which ? emb2 : emb1;
    const float* cb = which ? cb2 : cb1;
    int V = which ? 65 : 5;
    __shared__ float Wsh[65 * KS];
    __shared__ float ych[OUTT];
    if (which) {
        const float* Wrow = Wl + (b * NF + o) * 65 * KS;
        for (int j = t; j < 65 * KS; j += 128) Wsh[j] = Wrow[j];
    } else {
        for (int j = t; j < 5 * KS; j += 128) {
            int v = j >> 3, k = j & 7;
            const float* p = Wpg + (b * 5 + v) * SEG_G * 256 + o * 8 + k;
            float s = 0.f;
            #pragma unroll
            for (int g = 0; g < SEG_G; g++) s += p[g * 256];
            Wsh[j] = s;
        }
    }
    __syncthreads();
    if (t < OUTT) {
        float acc = cb[o];
        for (int v = 0; v < V; v++) {
            const float* ep = emb + v * EMB + t;
            #pragma unroll
            for (int k = 0; k < KS; k++) acc += Wsh[v * KS + k] * ep[k];
        }
        ych[t] = acc;
    }
    __syncthreads();
    float facc = 0.f;
    const float* wp = w + (o * OUTT) * EMB + t;
    #pragma unroll 4
    for (int jj = 0; jj < OUTT; jj++) facc += ych[jj] * wp[jj * EMB];
    partial[((which * BGR + b) * NKC + o) * EMB + t] = facc;
}

// merged fcred + xp (final outputs)
__global__ void __launch_bounds__(128) k_tail(const float* __restrict__ partial,
                                              const float* __restrict__ bias,
                                              const float* __restrict__ gsum,
                                              const float* __restrict__ gcnt,
                                              const float* __restrict__ w,
                                              const float* __restrict__ xpb,
                                              float* __restrict__ out) {
    int b = blockIdx.x;
    int e = threadIdx.x;
    if (blockIdx.y == 0) {
        const float* pg = partial + b * NKC * EMB + e;
        const float* pl = partial + (BGR + b) * NKC * EMB + e;
        float ag = bias[e], al = bias[e];
        #pragma unroll
        for (int k = 0; k < NKC; k++) { ag += pg[k * EMB]; al += pl[k * EMB]; }
        out[b * EMB + e] = 0.5f * (ag + al);
    } else {
        float inv = 1.f / fmaxf(gcnt[b], 1.f);
        float acc = xpb[e];
        #pragma unroll
        for (int f = 0; f < DIM; f++) acc += gsum[b * DIM + f] * inv * w[f * EMB + e];
        out[BGR * EMB + b * EMB + e] = fmaxf(acc, 0.f);
    }
}

extern "C" void kernel_launch(void* const* d_in, const int* in_sizes, int n_in,
                              void* d_out, int out_size, void* d_ws, size_t ws_size,
                              hipStream_t stream) {
    const float* pro_x = (const float*)d_in[0];
    const int* eidx = (const int*)d_in[1];
    const int* esrc = eidx;
    const int* edst = eidx + N_EDGES;
    const float* pw = (const float*)d_in[2];
    const int* batch = (const int*)d_in[3];
    const int* rg = (const int*)d_in[4];
    const int* rl = (const int*)d_in[5];
    const float* g1_w1 = (const float*)d_in[6];
    const float* g1_b1 = (const float*)d_in[7];
    const float* g1_w2 = (const float*)d_in[8];
    const float* g1_b2 = (const float*)d_in[9];
    const float* g1_ew = (const float*)d_in[10];
    const float* g1_eb = (const float*)d_in[11];
    const float* g1_eps = (const float*)d_in[12];
    const float* g_w1 = (const float*)d_in[13];
    const float* g_b1 = (const float*)d_in[14];
    const float* g_w2 = (const float*)d_in[15];
    const float* g_b2 = (const float*)d_in[16];
    const float* g_ew = (const float*)d_in[17];
    const float* g_eb = (const float*)d_in[18];
    const float* g_eps = (const float*)d_in[19];
    const float* bn_gamma = (const float*)d_in[20];
    const float* bn_beta = (const float*)d_in[21];
    const float* fc1_xp_w = (const float*)d_in[22];
    const float* fc1_xp_b = (const float*)d_in[23];
    const float* emb1 = (const float*)d_in[24];
    const float* emb2 = (const float*)d_in[25];
    const float* convr1_w = (const float*)d_in[26];
    const float* convr1_b = (const float*)d_in[27];
    const float* convr2_w = (const float*)d_in[28];
    const float* convr2_b = (const float*)d_in[29];
    const float* fcxr_w = (const float*)d_in[30];
    const float* fcxr_b = (const float*)d_in[31];
    float* out = (float*)d_out;

    // persistent buffers
    float* wsf = (float*)d_ws;
    int* ptr       = (int*)wsf;        wsf += 100128;
    int* binoff    = (int*)wsf;        wsf += 512;
    int* bincur    = (int*)wsf;        wsf += 512;
    unsigned* er   = (unsigned*)wsf;   wsf += 2 * N_EDGES;
    float* stats   = wsf;              wsf += 1280;
    // union region lifetimes:
    //   tmp_sw/bh die after part2; cwT/W* die after yfc; blists/bptrs die after wsum;
    //   fcpart (un+6600000..7124288, over dead blists) lives k_yfc -> k_tail, ends
    //   BEFORE h (7400000) so the GNN stack cannot clobber it; h lives agg/mlp phases.
    float* un = wsf;
    int2* tmp_sw = (int2*)un;                    // 0 .. 6400000
    int* bh      = (int*)(un + 7200000);         // 7200000 .. 7400192
    float* cwTg  = un;                           // 0 .. 768000   (after part2)
    float* cwTl  = un + 768000;                  // .. 1535488
    __half* zh   = (__half*)(un + 1600000);      // .. 2400000
    __half* xh1  = (__half*)(un + 2400000);      // .. 4000000
    __half* xh32 = (__half*)(un + 4000000);      // .. 4050000
    float* Wpg   = un + 4300000;                 // .. 4955360
    float* Wl    = un + 5000000;                 // .. 6064960
    int* blg     = (int*)(un + 6600000);         // .. 6792000 (dies after wsum)
    int* bll     = (int*)(un + 6800000);         // .. 6991872 (dies after wsum)
    int* bpg     = (int*)(un + 7000000);         // .. 7000384 (dies after wsum)
    int* bpl     = (int*)(un + 7001000);         // .. 7005224 (dies after wsum)
    float* fcpart = un + 6600000;                // .. 7124288 (yfc -> tail; < h start)
    float* h      = un + 7400000;                // .. 11000000
    float* gsum   = stats;
    float* gcnt   = stats + 1024;
    float* bnstat = stats + 1088;

    hipMemsetAsync(stats, 0, 1280 * sizeof(float), stream);

    // CSR build + RNA bucketing (merged independent work)
    k_pre1<<<BCNT_BLK + 128, 256, 0, stream>>>(edst, bh, rg, rl, blg, bpg, bll, bpl);
    k_binscan<<<1, 512, 0, stream>>>(bh, binoff, bincur);
    k_part1<<<P1_BLOCKS, 256, 0, stream>>>(esrc, edst, pw, bincur, tmp_sw);
    k_part2<<<NBIN, 256, 0, stream>>>(tmp_sw, binoff, er, ptr);

    // conv weight transpose + pro_x fp16 (both overwrite dead tmp_sw region)
    k_pre2<<<MAXLEN + LOCLEN + (N_NODES * NFP + 255) / 256, 256, 0, stream>>>(
        convr1_w, convr2_w, cwTg, cwTl, pro_x, xh1, xh32);

    // RNA branch
    k_wsum<<<dim3(BGR, 105), 256, 0, stream>>>(blg, bpg, bll, bpl, cwTg, cwTl, Wpg, Wl);
    k_yfc<<<dim3(BGR * NF, 2), 128, 0, stream>>>(Wpg, Wl, emb1, emb2, convr1_b, convr2_b,
                                                 fcxr_w, fcpart);

    // GNN stack (round-8 proven kernels: separate agg16 + mlp16)
    k_agg1<<<AGGB1, 256, 0, stream>>>(xh1, xh32, ptr, er, g1_ew, g1_eb, g1_eps, h);
    k_mlp1<<<MLPB, 256, 0, stream>>>(h, g1_w1, g1_b1, g1_w2, g1_b2, zh, bnstat);
    for (int i = 0; i < 4; i++) {
        k_agg16<<<AGGB16, 256, 0, stream>>>(zh, ptr, er,
                                            g_ew + i * DIM, g_eb + i * DIM, g_eps + i,
                                            bnstat + i * 32, bn_gamma + i * DIM,
                                            bn_beta + i * DIM, h);
        k_mlp16<<<MLPB, 256, 0, stream>>>(h, g_w1 + i * DIM * DIM, g_b1 + i * DIM,
                                          g_w2 + i * DIM * DIM, g_b2 + i * DIM, zh,
                                          bnstat + (i + 1) * 32);
    }
    k_pool<<<POOL_BLKS, 256, 0, stream>>>(zh, batch, bnstat + 4 * 32,
                                          bn_gamma + 4 * DIM, bn_beta + 4 * DIM, gsum, gcnt);
    // final outputs (fcred + xp merged; fcpart intact below h)
    k_tail<<<dim3(BGR, 2), 128, 0, stream>>>(fcpart, fcxr_b, gsum, gcnt,
                                             fc1_xp_w, fc1_xp_b, out);
}